// Round 7
// baseline (581.311 us; speedup 1.0000x reference)
//
#include <hip/hip_runtime.h>

// P2M loss. B=2, M=8192, V={642,2562,10242}, E={1920,7680,30720}
// MFMA chamfer: d = |p|^2+|g|^2-2p.g on the matrix pipe via bf16 3-term
// truncation split (fp32-accurate, dropped terms <=2^-24): K=24 of 32 =>
// ONE mfma_f32_16x16x32_bf16 per 16x16 distance tile. v6 structure
// (pack-in-block + LDS staging + combine-coalesced partials + 2-deep named
// MFMA pipeline). v7: per-vg vmin kept in NAMED regs vm0..vm7 (8-deep
// batches), cross-lane shfl merges hoisted OUT of the loop as independent
// chains (kills the per-vg serial bpermute stall); GML stride 17 (kills
// 4-way LDS write conflict).
//
// ws layout (bytes):
//   0      : float acc
//   4      : uint  ticket
//   8      : float lapPartials[128]
//   1024   : int   knn[13446]            (level offsets 0/642/3204)
//   STORE  : pA f32 [28160 vs][16 gtt]  @55296    (1,802,240)
//            vs = b*14080 + padOff{0,768,3584} + vtl*256 + i (wrap-dup tails)
//            pB f32 per (b,lvl): [8192 m][nt] @1857536 (3,604,480) end 5,462,016
//            float bases: b*450560 + {0, 24576, 114688}; nt = {3,11,41}
//   ATOMIC : pA u32[28160] @54808 ; pB u32[49152] @167448 (end 364,056, memset 0xFF)

#define DEV __device__ __forceinline__

typedef __attribute__((ext_vector_type(8))) short bs8;
typedef __attribute__((ext_vector_type(4))) float f32x4;

#define PA_S 55296
#define PB_S 1857536
#define PA_U 54808
#define PB_U 167448

DEV float blockReduceSum256(float v) {
    #pragma unroll
    for (int o = 32; o > 0; o >>= 1) v += __shfl_down(v, o, 64);
    __shared__ float red4[4];
    int wid = threadIdx.x >> 6;
    if ((threadIdx.x & 63) == 0) red4[wid] = v;
    __syncthreads();
    return (threadIdx.x == 0) ? (red4[0] + red4[1] + red4[2] + red4[3]) : 0.0f;
}

// 3-term bf16 truncation split: u ~= h+m+l with residual <= 2^-24*|u|
DEV void split3(float u, unsigned short& h, unsigned short& m, unsigned short& l) {
    unsigned a = __float_as_uint(u);
    h = (unsigned short)(a >> 16);
    float r1 = u - __uint_as_float(a & 0xFFFF0000u);
    unsigned bb = __float_as_uint(r1);
    m = (unsigned short)(bb >> 16);
    float r2 = r1 - __uint_as_float(bb & 0xFFFF0000u);
    l = (unsigned short)(__float_as_uint(r2) >> 16);
}

// A operand row (gt point g): per coord (h,h,m,h,l,m); k18..23 = [nh,nm,nl,1,1,1]
DEV void packGT(const float* __restrict__ gp, char* dst) {
    float x = gp[0], y = gp[1], z = gp[2];
    unsigned short hx,mx,lx, hy,my,ly, hz,mz,lz, nh,nm,nl;
    split3(x,hx,mx,lx); split3(y,hy,my,ly); split3(z,hz,mz,lz);
    float n = fmaf(x,x,fmaf(y,y,z*z));
    split3(n,nh,nm,nl);
    const short ONE = (short)0x3F80;
    bs8 w0 = {(short)hx,(short)hx,(short)mx,(short)hx,(short)lx,(short)mx,(short)hy,(short)hy};
    bs8 w1 = {(short)my,(short)hy,(short)ly,(short)my,(short)hz,(short)hz,(short)mz,(short)hz};
    bs8 w2 = {(short)lz,(short)mz,(short)nh,(short)nm,(short)nl,ONE,ONE,ONE};
    bs8 w3 = {0,0,0,0,0,0,0,0};
    *(bs8*)(dst)       = w0;
    *(bs8*)(dst + 256) = w1;
    *(bs8*)(dst + 512) = w2;
    *(bs8*)(dst + 768) = w3;
}

// B operand col (vert p, u=-2p): per coord (h,m,h,l,h,m); k18..23 = [1,1,1,nh,nm,nl]
DEV void packVERT(const float* __restrict__ pp, char* dst) {
    float x = pp[0], y = pp[1], z = pp[2];
    unsigned short hx,mx,lx, hy,my,ly, hz,mz,lz, nh,nm,nl;
    split3(-2.f*x,hx,mx,lx); split3(-2.f*y,hy,my,ly); split3(-2.f*z,hz,mz,lz);
    float n = fmaf(x,x,fmaf(y,y,z*z));
    split3(n,nh,nm,nl);
    const short ONE = (short)0x3F80;
    bs8 w0 = {(short)hx,(short)mx,(short)hx,(short)lx,(short)hx,(short)mx,(short)hy,(short)my};
    bs8 w1 = {(short)hy,(short)ly,(short)hy,(short)my,(short)hz,(short)mz,(short)hz,(short)lz};
    bs8 w2 = {(short)hz,(short)mz,ONE,ONE,ONE,(short)nh,(short)nm,(short)nl};
    bs8 w3 = {0,0,0,0,0,0,0,0};
    *(bs8*)(dst)       = w0;
    *(bs8*)(dst + 256) = w1;
    *(bs8*)(dst + 512) = w2;
    *(bs8*)(dst + 768) = w3;
}

// consume one MFMA tile result: gt-side mins + vert-side min (+embed)
#define CONSUME(ACC, GG, VM) do { \
    gmin[GG][0] = fminf(gmin[GG][0], (ACC)[0]); \
    gmin[GG][1] = fminf(gmin[GG][1], (ACC)[1]); \
    gmin[GG][2] = fminf(gmin[GG][2], (ACC)[2]); \
    gmin[GG][3] = fminf(gmin[GG][3], (ACC)[3]); \
    float t_ = fminf(fminf((ACC)[0], (ACC)[1]), fminf((ACC)[2], (ACC)[3])); \
    if (B0) { \
        t_ = fmaxf(t_, 0.0f); \
        t_ = __uint_as_float((__float_as_uint(t_) & embedMask) \
                             | (unsigned)(embedBase + 4 * (GG))); \
    } \
    VM = fminf(VM, t_); \
} while (0)

// one vert-panel body: 2-deep MFMA pipeline, named accumulators (order == v6)
#define VG_BODY(VG, VM) do { \
    bs8 bfn_ = bf; \
    if ((VG) < 15) bfn_ = *(const bs8*)(bbase + ((VG) + 1) * 1024); \
    float vminA_ = 3.0e38f, vminB_ = 3.0e38f; \
    f32x4 accA_ = __builtin_amdgcn_mfma_f32_16x16x32_bf16(af[0], bf, zero, 0, 0, 0); \
    f32x4 accB_ = __builtin_amdgcn_mfma_f32_16x16x32_bf16(af[1], bf, zero, 0, 0, 0); \
    f32x4 ca_, cb_; \
    ca_ = accA_; accA_ = __builtin_amdgcn_mfma_f32_16x16x32_bf16(af[2], bf, zero, 0, 0, 0); \
    CONSUME(ca_, 0, vminA_); \
    cb_ = accB_; accB_ = __builtin_amdgcn_mfma_f32_16x16x32_bf16(af[3], bf, zero, 0, 0, 0); \
    CONSUME(cb_, 1, vminB_); \
    ca_ = accA_; accA_ = __builtin_amdgcn_mfma_f32_16x16x32_bf16(af[4], bf, zero, 0, 0, 0); \
    CONSUME(ca_, 2, vminA_); \
    cb_ = accB_; accB_ = __builtin_amdgcn_mfma_f32_16x16x32_bf16(af[5], bf, zero, 0, 0, 0); \
    CONSUME(cb_, 3, vminB_); \
    ca_ = accA_; accA_ = __builtin_amdgcn_mfma_f32_16x16x32_bf16(af[6], bf, zero, 0, 0, 0); \
    CONSUME(ca_, 4, vminA_); \
    cb_ = accB_; accB_ = __builtin_amdgcn_mfma_f32_16x16x32_bf16(af[7], bf, zero, 0, 0, 0); \
    CONSUME(cb_, 5, vminB_); \
    CONSUME(accA_, 6, vminA_); \
    CONSUME(accB_, 7, vminB_); \
    VM = fminf(vminA_, vminB_); \
    bf = bfn_; \
} while (0)

// merge the 4 row-group copies of one vert panel (independent chains)
#define VMERGE(VM, VG) do { \
    float v_ = fminf(VM, __shfl_xor(VM, 16)); \
    v_ = fminf(v_, __shfl_xor(v_, 32)); \
    if (L < 16) *(float*)(VML + (((VG) * 16 + lr) * 4 + w) * 4) = v_; \
} while (0)

// Per wave: A = 8 resident gt panels (rows w*128..+128), 16 vert panels.
// acc row = gt = w*128+gg*16+lg*4+r ; acc col = vert = vg*16+lr.
template<bool B0>
DEV void mfmaLoop(const char* SA, const char* SB, char* VML,
                  float (&gmin)[8][4], int embedBase, unsigned embedMask)
{
    const int tid = threadIdx.x;
    const int w = tid >> 6, L = tid & 63, lr = L & 15;
    const char* abase = SA + (w * 8) * 1024 + (L >> 4) * 256 + lr * 16;
    bs8 af[8];
    #pragma unroll
    for (int g = 0; g < 8; g++) af[g] = *(const bs8*)(abase + g * 1024);
    const f32x4 zero = {0.f, 0.f, 0.f, 0.f};
    const char* bbase = SB + (L >> 4) * 256 + lr * 16;
    bs8 bf = *(const bs8*)(bbase);
    float vm0, vm1, vm2, vm3, vm4, vm5, vm6, vm7;
    VG_BODY(0, vm0); VG_BODY(1, vm1); VG_BODY(2, vm2); VG_BODY(3, vm3);
    VG_BODY(4, vm4); VG_BODY(5, vm5); VG_BODY(6, vm6); VG_BODY(7, vm7);
    VMERGE(vm0, 0); VMERGE(vm1, 1); VMERGE(vm2, 2); VMERGE(vm3, 3);
    VMERGE(vm4, 4); VMERGE(vm5, 5); VMERGE(vm6, 6); VMERGE(vm7, 7);
    VG_BODY(8, vm0); VG_BODY(9, vm1); VG_BODY(10, vm2); VG_BODY(11, vm3);
    VG_BODY(12, vm4); VG_BODY(13, vm5); VG_BODY(14, vm6); VG_BODY(15, vm7);
    VMERGE(vm0, 8);  VMERGE(vm1, 9);  VMERGE(vm2, 10); VMERGE(vm3, 11);
    VMERGE(vm4, 12); VMERGE(vm5, 13); VMERGE(vm6, 14); VMERGE(vm7, 15);
}

// mega: lap [0,128) | chamfer [128, 128+1760): cid = t2*16 + gtt
template<bool STORE>
__global__ __launch_bounds__(256, 3) void kMega2(
    const float* __restrict__ p0, const float* __restrict__ p1, const float* __restrict__ p2,
    const float* __restrict__ b0p, const float* __restrict__ b1p, const float* __restrict__ b2p,
    const int* __restrict__ l0, const int* __restrict__ l1, const int* __restrict__ l2,
    const float* __restrict__ gt, char* ws)
{
    extern __shared__ char smem[];
    int bid = blockIdx.x;
    if (bid == 0 && threadIdx.x == 0) { *(float*)ws = 0.f; *(unsigned*)(ws + 4) = 0u; }
    if (bid < 128) {
        float c = 0.0f;
        int idx = bid * 256 + threadIdx.x;
        if (idx < 26892) {
            int level, V, t;
            const float *pred, *bef; const int* lap;
            if (idx < 1284)      { level = 0; V = 642;   pred = p0; bef = b0p; lap = l0; t = idx; }
            else if (idx < 6408) { level = 1; V = 2562;  pred = p1; bef = b1p; lap = l1; t = idx - 1284; }
            else                 { level = 2; V = 10242; pred = p2; bef = b2p; lap = l2; t = idx - 6408; }
            int b = t / V;
            int v = t - b * V;
            const float* P  = pred + ((size_t)b * V + v) * 3;
            const float* Bf = bef  + ((size_t)b * V + v) * 3;
            float dx = Bf[0] - P[0], dy = Bf[1] - P[1], dz = Bf[2] - P[2];
            float sx = 0.f, sy = 0.f, sz = 0.f;
            const int* Lp = lap + v * 10;
            #pragma unroll
            for (int j = 0; j < 8; j++) {
                int n = Lp[j];
                if (n >= 0) {
                    const float* Pn = pred + ((size_t)b * V + n) * 3;
                    const float* Bn = bef  + ((size_t)b * V + n) * 3;
                    sx += Bn[0] - Pn[0]; sy += Bn[1] - Pn[1]; sz += Bn[2] - Pn[2];
                }
            }
            float invc = 1.0f / (float)Lp[9];
            float lx = dx - sx * invc, ly = dy - sy * invc, lz = dz - sz * invc;
            float sl = fmaf(lx, lx, fmaf(ly, ly, lz * lz));
            float sm = fmaf(dx, dx, fmaf(dy, dy, dz * dz));
            float lapc = (level == 0) ? 0.2f : 1.0f;
            float iBV = 1.0f / (2.0f * (float)V);
            c = sl * (0.5f * lapc * iBV) + ((level > 0) ? sm * (0.1f * lapc * iBV) : 0.0f);
        }
        c = blockReduceSum256(c);
        if (threadIdx.x == 0) ((float*)(ws + 8))[bid] = c;
        return;
    }
    int cid = bid - 128;
    int gtt = cid & 15;                // gt tile (512 pts)
    int t2 = cid >> 4;                 // 0..109
    int b = t2 >= 55 ? 1 : 0;
    int vt = t2 - 55 * b;
    int lvl, vtl, V, padOff, nt, tb;
    if (vt < 3)       { lvl = 0; vtl = vt;      V = 642;   padOff = 0;    nt = 3;  tb = 0; }
    else if (vt < 14) { lvl = 1; vtl = vt - 3;  V = 2562;  padOff = 768;  nt = 11; tb = 3; }
    else              { lvl = 2; vtl = vt - 14; V = 10242; padOff = 3584; nt = 41; tb = 14; }
    const float* predL = lvl == 0 ? p0 : (lvl == 1 ? p1 : p2);
    char* SA  = smem;            // 32 KB: 32 gt panels [panel][kgroup][row][16B]
    char* SB  = smem + 32768;    // 16 KB: 16 vert panels
    char* VML = smem + 49152;    //  4 KB: vert partial [256][4 waves] f32
    int tid = threadIdx.x;
    {   // stage 256 verts (wrap-duplicate tail; duplicates are min-safe)
        int v = vtl * 256 + tid;
        if (v >= V) v -= V;
        packVERT(predL + ((size_t)b * V + v) * 3, SB + (tid >> 4) * 1024 + (tid & 15) * 16);
    }
    #pragma unroll
    for (int k = 0; k < 2; k++) {    // stage 512 gts
        int j = tid + k * 256;
        packGT(gt + ((size_t)b * 8192 + gtt * 512 + j) * 3, SA + (j >> 4) * 1024 + (j & 15) * 16);
    }
    __syncthreads();
    float gmin[8][4];
    #pragma unroll
    for (int g = 0; g < 8; g++) {
        gmin[g][0] = 3.0e38f; gmin[g][1] = 3.0e38f; gmin[g][2] = 3.0e38f; gmin[g][3] = 3.0e38f;
    }
    int w = tid >> 6, L = tid & 63, lg = L >> 4;
    if (b == 0) {
        unsigned mask = STORE ? 0xFFFFFF80u : 0xFFFFF800u;  // 7-bit / 11-bit (+gtt) embed
        int eb = w * 32 + lg + (STORE ? 0 : (gtt << 7));
        mfmaLoop<true>(SA, SB, VML, gmin, eb, mask);
    } else {
        mfmaLoop<false>(SA, SB, VML, gmin, 0, 0u);
    }
    __syncthreads();                 // all reads of SA/SB done -> reuse as GML
    float* GML = (float*)smem;       // [512 gt][stride 17] f32 = 34,816 B
    #pragma unroll
    for (int gg = 0; gg < 8; gg++) {
        #pragma unroll
        for (int r = 0; r < 4; r++)
            GML[(w * 128 + gg * 16 + lg * 4 + r) * 17 + (L & 15)] = gmin[gg][r];
    }
    __syncthreads();
    {   // vert partial: thread tid owns vert tid; pA[vs][gtt] (combine-coalesced)
        float4 vv = *(float4*)(VML + tid * 16);
        float pv = fminf(fminf(vv.x, vv.y), fminf(vv.z, vv.w));
        int vs = b * 14080 + padOff + vtl * 256 + tid;
        if (STORE) {
            ((float*)(ws + PA_S))[(size_t)vs * 16 + gtt] = pv;
        } else {
            if (vtl * 256 + tid < V)
                atomicMin((unsigned*)(ws + PA_U) + vs, __float_as_uint(fmaxf(pv, 0.0f)));
        }
    }
    {   // gt partials: thread handles gts tid, tid+256; pB[(b,lvl)][m][tile]
        size_t pbBase = (size_t)b * 450560 + (lvl == 0 ? 0 : (lvl == 1 ? 24576 : 114688));
        #pragma unroll
        for (int k = 0; k < 2; k++) {
            int g = tid + k * 256;
            float q = 3.0e38f;
            #pragma unroll
            for (int cc = 0; cc < 16; cc++)
                q = fminf(q, GML[g * 17 + ((cc + tid) & 15)]);
            if (STORE) {
                ((float*)(ws + PB_S))[pbBase + (size_t)(gtt * 512 + g) * nt + vtl] = q;
            } else {
                atomicMin((unsigned*)(ws + PB_U) + (((b * 3 + lvl) << 13) + gtt * 512 + g),
                          __float_as_uint(fmaxf(q, 0.0f)));
            }
        }
    }
}

// combine: vert slots [0,28160) | gt slots [28160,77312) | lap-sum block 302
template<bool STORE>
__global__ __launch_bounds__(256) void kCombine2(
    const float* __restrict__ p0, const float* __restrict__ p1, const float* __restrict__ p2,
    const float* __restrict__ gt, char* ws)
{
    int bid = blockIdx.x, tid = threadIdx.x;
    float c = 0.0f;
    if (bid == 302) {
        if (tid < 128) c = ((float*)(ws + 8))[tid];
    } else {
        int idx = bid * 256 + tid;
        if (idx < 28160) {
            int b = idx >= 14080 ? 1 : 0;
            int q = idx - b * 14080;
            int lvl, V, lvlOff, padOff; const float* predL; float inv;
            if (q < 768)       { lvl=0; V=642;   padOff=0;    lvlOff=0;    predL=p0; inv=1.f/1284.f; }
            else if (q < 3584) { lvl=1; V=2562;  padOff=768;  lvlOff=642;  predL=p1; inv=1.f/5124.f; }
            else               { lvl=2; V=10242; padOff=3584; lvlOff=3204; predL=p2; inv=1.f/20484.f; }
            int v = q - padOff;
            if (v < V) {                               // skip wrap-duplicate slots
                float best; int bt = 0; unsigned bits;
                if (STORE) {
                    // contiguous 64B scan (4x float4)
                    const float4* P4 = (const float4*)((const float*)(ws + PA_S) + (size_t)idx * 16);
                    float4 a0 = P4[0], a1 = P4[1], a2 = P4[2], a3 = P4[3];
                    float vals[16] = {a0.x,a0.y,a0.z,a0.w, a1.x,a1.y,a1.z,a1.w,
                                      a2.x,a2.y,a2.z,a2.w, a3.x,a3.y,a3.z,a3.w};
                    best = vals[0];
                    #pragma unroll
                    for (int t = 1; t < 16; t++)
                        if (vals[t] < best) { best = vals[t]; bt = t; }
                    bits = __float_as_uint(best);
                } else {
                    bits = ((const unsigned*)(ws + PA_U))[idx];
                    best = __uint_as_float(bits);
                    bt = (bits >> 7) & 15;
                }
                float d;
                if (b == 0) {
                    // decode gt-group-of-4, recompute the 4 candidates exactly
                    int code = bits & 0x7F;
                    int m0 = bt * 512 + code * 4;
                    const float* pp = predL + (size_t)v * 3;
                    float px = pp[0], py = pp[1], pz = pp[2];
                    float bd = 3.0e38f; int bm = m0;
                    #pragma unroll
                    for (int u2 = 0; u2 < 4; u2++) {
                        const float* gp = gt + (size_t)(m0 + u2) * 3;
                        float dx = px - gp[0], dy = py - gp[1], dz = pz - gp[2];
                        float dd = fmaf(dx, dx, fmaf(dy, dy, dz * dz));
                        if (dd < bd) { bd = dd; bm = m0 + u2; }
                    }
                    ((int*)(ws + 1024))[lvlOff + v] = bm;
                    d = bd;
                } else {
                    d = best;                           // raw fp32, no embed for b=1
                }
                c = d * inv;
            }
        } else if (idx < 77312) {
            int r = idx - 28160;
            int b = r >= 24576 ? 1 : 0;
            int rem = r - b * 24576;
            int lvl = rem >> 13, m = rem & 8191;
            float d;
            if (STORE) {
                int nt = lvl == 0 ? 3 : (lvl == 1 ? 11 : 41);
                size_t pbBase = (size_t)b * 450560 + (lvl == 0 ? 0 : (lvl == 1 ? 24576 : 114688));
                const float* P = (const float*)(ws + PB_S) + pbBase + (size_t)m * nt;
                d = P[0];
                #pragma unroll 4
                for (int k2 = 1; k2 < nt; k2++) d = fminf(d, P[k2]);
            } else {
                d = __uint_as_float(((const unsigned*)(ws + PB_U))[((b * 3 + lvl) << 13) + m]);
            }
            c = d * (1.f / 16384.f);
        }
    }
    c = blockReduceSum256(c);
    if (tid == 0) atomicAdd((float*)ws, c);
}

// ---------- edge + normal + final output (ticket) ----------
__global__ __launch_bounds__(256) void kEdgeOut(
    const float* __restrict__ p0, const float* __restrict__ p1, const float* __restrict__ p2,
    const int* __restrict__ e0p, const int* __restrict__ e1p, const int* __restrict__ e2p,
    const float* __restrict__ gtn, char* ws, float* __restrict__ out)
{
    const int* knn = (const int*)(ws + 1024);
    int idx = blockIdx.x * 256 + threadIdx.x;
    float c = 0.0f;
    {
        int E, V, lvlOff, t;
        const float* pred; const int* edges;
        if (idx < 3840)       { E = 1920;  V = 642;   lvlOff = 0;    pred = p0; edges = e0p; t = idx; }
        else if (idx < 19200) { E = 7680;  V = 2562;  lvlOff = 642;  pred = p1; edges = e1p; t = idx - 3840; }
        else                  { E = 30720; V = 10242; lvlOff = 3204; pred = p2; edges = e2p; t = idx - 19200; }
        int b = t / E;
        int e = t % E;
        int a0 = edges[e * 2 + 0];
        int a1 = edges[e * 2 + 1];
        const float* P = pred + (size_t)b * V * 3;
        float dx = P[a0 * 3 + 0] - P[a1 * 3 + 0];
        float dy = P[a0 * 3 + 1] - P[a1 * 3 + 1];
        float dz = P[a0 * 3 + 2] - P[a1 * 3 + 2];
        float sq = fmaf(dx, dx, fmaf(dy, dy, dz * dz));
        float inv = 1.0f / fmaxf(sqrtf(sq), 1e-12f);
        int sel = knn[lvlOff + a0];                          // b=0 argmin
        const float* nr = gtn + ((size_t)b * 8192 + sel) * 3;
        float nx = nr[0], ny = nr[1], nz = nr[2];
        float invn = 1.0f / fmaxf(sqrtf(fmaf(nx, nx, fmaf(ny, ny, nz * nz))), 1e-12f);
        float dotv = fmaf(dx, nx, fmaf(dy, ny, dz * nz)) * inv * invn;
        float iBE = 1.0f / (2.0f * (float)E);
        c = sq * (0.1f * iBE) + fabsf(dotv) * (0.00016f * iBE);
    }
    c = blockReduceSum256(c);
    if (threadIdx.x == 0) {
        atomicAdd((float*)ws, c);
        __threadfence();
        unsigned t = atomicAdd((unsigned*)(ws + 4), 1u);
        if (t == 314u) out[0] = atomicAdd((float*)ws, 0.0f);
    }
}

extern "C" void kernel_launch(void* const* d_in, const int* in_sizes, int n_in,
                              void* d_out, int out_size, void* d_ws, size_t ws_size,
                              hipStream_t stream) {
    const float *gt, *gtn, *pred[3], *bef[3];
    const int *edg[3], *lapx[3];
    if (in_sizes[0] == 49152) {
        gt  = (const float*)d_in[0];
        gtn = (const float*)d_in[1];
        for (int i = 0; i < 3; i++) {
            pred[i] = (const float*)d_in[2 + 4 * i];
            bef[i]  = (const float*)d_in[3 + 4 * i];
            edg[i]  = (const int*)  d_in[4 + 4 * i];
            lapx[i] = (const int*)  d_in[5 + 4 * i];
        }
    } else {
        for (int i = 0; i < 3; i++) pred[i] = (const float*)d_in[i];
        for (int i = 0; i < 3; i++) bef[i]  = (const float*)d_in[3 + i];
        gt  = (const float*)d_in[6];
        gtn = (const float*)d_in[7];
        for (int i = 0; i < 3; i++) lapx[i] = (const int*)d_in[8 + i];
        for (int i = 0; i < 3; i++) edg[i]  = (const int*)d_in[11 + i];
    }

    char* ws = (char*)d_ws;
    bool store = ws_size >= (size_t)5462016;

    if (store) {
        kMega2<true><<<1888, 256, 53248, stream>>>(pred[0], pred[1], pred[2],
                                                   bef[0], bef[1], bef[2],
                                                   lapx[0], lapx[1], lapx[2], gt, ws);
        kCombine2<true><<<303, 256, 0, stream>>>(pred[0], pred[1], pred[2], gt, ws);
    } else {
        hipMemsetAsync(ws + PA_U, 0xFF, 364056 - PA_U, stream);   // mins = large
        kMega2<false><<<1888, 256, 53248, stream>>>(pred[0], pred[1], pred[2],
                                                    bef[0], bef[1], bef[2],
                                                    lapx[0], lapx[1], lapx[2], gt, ws);
        kCombine2<false><<<303, 256, 0, stream>>>(pred[0], pred[1], pred[2], gt, ws);
    }
    kEdgeOut<<<315, 256, 0, stream>>>(pred[0], pred[1], pred[2],
                                      edg[0], edg[1], edg[2], gtn, ws, (float*)d_out);
}

// Round 8
// 125.191 us; speedup vs baseline: 4.6434x; 4.6434x over previous
//
#include <hip/hip_runtime.h>

// P2M loss. B=2, M=8192, V={642,2562,10242}, E={1920,7680,30720}
// MFMA chamfer: d = |p|^2+|g|^2-2p.g on the matrix pipe via bf16 3-term
// truncation split (fp32-accurate, dropped terms <=2^-24): K=24 of 32 =>
// ONE mfma_f32_16x16x32_bf16 per 16x16 distance tile. v6 structure
// (pack-in-block + LDS staging + combine-coalesced partials + 2-deep named
// MFMA pipeline, #pragma unroll 2 loop = register-safe envelope; v5/v7
// straight-line variants spilled). v8: per-vg vmin goes to LDS
// [256 vert][17] (fire-and-forget write, no dependent shfl tail, no
// live-range growth) reduced in epilogue; GML stride 17 (no 4-way conflict).
//
// ws layout (bytes):
//   0      : float acc
//   4      : uint  ticket
//   8      : float lapPartials[128]
//   1024   : int   knn[13446]            (level offsets 0/642/3204)
//   STORE  : pA f32 [28160 vs][16 gtt]  @55296    (1,802,240)
//            vs = b*14080 + padOff{0,768,3584} + vtl*256 + i (wrap-dup tails)
//            pB f32 per (b,lvl): [8192 m][nt] @1857536 (3,604,480) end 5,462,016
//            float bases: b*450560 + {0, 24576, 114688}; nt = {3,11,41}
//   ATOMIC : pA u32[28160] @54808 ; pB u32[49152] @167448 (end 364,056, memset 0xFF)

#define DEV __device__ __forceinline__

typedef __attribute__((ext_vector_type(8))) short bs8;
typedef __attribute__((ext_vector_type(4))) float f32x4;

#define PA_S 55296
#define PB_S 1857536
#define PA_U 54808
#define PB_U 167448

DEV float blockReduceSum256(float v) {
    #pragma unroll
    for (int o = 32; o > 0; o >>= 1) v += __shfl_down(v, o, 64);
    __shared__ float red4[4];
    int wid = threadIdx.x >> 6;
    if ((threadIdx.x & 63) == 0) red4[wid] = v;
    __syncthreads();
    return (threadIdx.x == 0) ? (red4[0] + red4[1] + red4[2] + red4[3]) : 0.0f;
}

// 3-term bf16 truncation split: u ~= h+m+l with residual <= 2^-24*|u|
DEV void split3(float u, unsigned short& h, unsigned short& m, unsigned short& l) {
    unsigned a = __float_as_uint(u);
    h = (unsigned short)(a >> 16);
    float r1 = u - __uint_as_float(a & 0xFFFF0000u);
    unsigned bb = __float_as_uint(r1);
    m = (unsigned short)(bb >> 16);
    float r2 = r1 - __uint_as_float(bb & 0xFFFF0000u);
    l = (unsigned short)(__float_as_uint(r2) >> 16);
}

// A operand row (gt point g): per coord (h,h,m,h,l,m); k18..23 = [nh,nm,nl,1,1,1]
DEV void packGT(const float* __restrict__ gp, char* dst) {
    float x = gp[0], y = gp[1], z = gp[2];
    unsigned short hx,mx,lx, hy,my,ly, hz,mz,lz, nh,nm,nl;
    split3(x,hx,mx,lx); split3(y,hy,my,ly); split3(z,hz,mz,lz);
    float n = fmaf(x,x,fmaf(y,y,z*z));
    split3(n,nh,nm,nl);
    const short ONE = (short)0x3F80;
    bs8 w0 = {(short)hx,(short)hx,(short)mx,(short)hx,(short)lx,(short)mx,(short)hy,(short)hy};
    bs8 w1 = {(short)my,(short)hy,(short)ly,(short)my,(short)hz,(short)hz,(short)mz,(short)hz};
    bs8 w2 = {(short)lz,(short)mz,(short)nh,(short)nm,(short)nl,ONE,ONE,ONE};
    bs8 w3 = {0,0,0,0,0,0,0,0};
    *(bs8*)(dst)       = w0;
    *(bs8*)(dst + 256) = w1;
    *(bs8*)(dst + 512) = w2;
    *(bs8*)(dst + 768) = w3;
}

// B operand col (vert p, u=-2p): per coord (h,m,h,l,h,m); k18..23 = [1,1,1,nh,nm,nl]
DEV void packVERT(const float* __restrict__ pp, char* dst) {
    float x = pp[0], y = pp[1], z = pp[2];
    unsigned short hx,mx,lx, hy,my,ly, hz,mz,lz, nh,nm,nl;
    split3(-2.f*x,hx,mx,lx); split3(-2.f*y,hy,my,ly); split3(-2.f*z,hz,mz,lz);
    float n = fmaf(x,x,fmaf(y,y,z*z));
    split3(n,nh,nm,nl);
    const short ONE = (short)0x3F80;
    bs8 w0 = {(short)hx,(short)mx,(short)hx,(short)lx,(short)hx,(short)mx,(short)hy,(short)my};
    bs8 w1 = {(short)hy,(short)ly,(short)hy,(short)my,(short)hz,(short)mz,(short)hz,(short)lz};
    bs8 w2 = {(short)hz,(short)mz,ONE,ONE,ONE,(short)nh,(short)nm,(short)nl};
    bs8 w3 = {0,0,0,0,0,0,0,0};
    *(bs8*)(dst)       = w0;
    *(bs8*)(dst + 256) = w1;
    *(bs8*)(dst + 512) = w2;
    *(bs8*)(dst + 768) = w3;
}

// consume one MFMA tile result: gt-side mins + vert-side min (+embed)
#define CONSUME(ACC, GG, VM) do { \
    gmin[GG][0] = fminf(gmin[GG][0], (ACC)[0]); \
    gmin[GG][1] = fminf(gmin[GG][1], (ACC)[1]); \
    gmin[GG][2] = fminf(gmin[GG][2], (ACC)[2]); \
    gmin[GG][3] = fminf(gmin[GG][3], (ACC)[3]); \
    float t_ = fminf(fminf((ACC)[0], (ACC)[1]), fminf((ACC)[2], (ACC)[3])); \
    if (B0) { \
        t_ = fmaxf(t_, 0.0f); \
        t_ = __uint_as_float((__float_as_uint(t_) & embedMask) \
                             | (unsigned)(embedBase + 4 * (GG))); \
    } \
    VM = fminf(VM, t_); \
} while (0)

// Per wave: A = 8 resident gt panels (rows w*128..+128), loop 16 vert panels.
// acc row = gt = w*128+gg*16+lg*4+r ; acc col = vert = vg*16+lr.
// 2-deep software pipeline with named accumulators (v6, register-safe).
// vmin goes straight to VML16[vert][copy] in LDS (copy = tid>>4): no
// cross-lane shuffles, no extended live ranges. VML16 overlays the SA
// region, which is dead after the one-time af[] loads (barrier below).
template<bool B0>
DEV void mfmaLoop(const char* SA, const char* SB, float* VML16,
                  float (&gmin)[8][4], int embedBase, unsigned embedMask)
{
    const int tid = threadIdx.x;
    const int w = tid >> 6, L = tid & 63, lr = L & 15;
    const int cp = tid >> 4;                       // copy index 0..15 (w*4+lg)
    const char* abase = SA + (w * 8) * 1024 + (L >> 4) * 256 + lr * 16;
    bs8 af[8];
    #pragma unroll
    for (int g = 0; g < 8; g++) af[g] = *(const bs8*)(abase + g * 1024);
    __syncthreads();                               // SA dead -> VML16 may overlay
    const f32x4 zero = {0.f, 0.f, 0.f, 0.f};
    const char* bbase = SB + (L >> 4) * 256 + lr * 16;
    bs8 bf = *(const bs8*)(bbase);
    #pragma unroll 2
    for (int vg = 0; vg < 16; vg++) {
        bs8 bfn = bf;
        if (vg < 15) bfn = *(const bs8*)(bbase + (vg + 1) * 1024);
        float vminA = 3.0e38f, vminB = 3.0e38f;
        f32x4 accA = __builtin_amdgcn_mfma_f32_16x16x32_bf16(af[0], bf, zero, 0, 0, 0);
        f32x4 accB = __builtin_amdgcn_mfma_f32_16x16x32_bf16(af[1], bf, zero, 0, 0, 0);
        #pragma unroll
        for (int gg = 0; gg < 8; gg += 2) {
            f32x4 ca = accA;
            if (gg < 6) accA = __builtin_amdgcn_mfma_f32_16x16x32_bf16(af[gg + 2], bf, zero, 0, 0, 0);
            CONSUME(ca, gg, vminA);
            f32x4 cb = accB;
            if (gg < 6) accB = __builtin_amdgcn_mfma_f32_16x16x32_bf16(af[gg + 3], bf, zero, 0, 0, 0);
            CONSUME(cb, gg + 1, vminB);
        }
        VML16[(vg * 16 + lr) * 17 + cp] = fminf(vminA, vminB);  // fire-and-forget
        bf = bfn;
    }
}

// mega: lap [0,128) | chamfer [128, 128+1760): cid = t2*16 + gtt
template<bool STORE>
__global__ __launch_bounds__(256, 3) void kMega2(
    const float* __restrict__ p0, const float* __restrict__ p1, const float* __restrict__ p2,
    const float* __restrict__ b0p, const float* __restrict__ b1p, const float* __restrict__ b2p,
    const int* __restrict__ l0, const int* __restrict__ l1, const int* __restrict__ l2,
    const float* __restrict__ gt, char* ws)
{
    extern __shared__ char smem[];
    int bid = blockIdx.x;
    if (bid == 0 && threadIdx.x == 0) { *(float*)ws = 0.f; *(unsigned*)(ws + 4) = 0u; }
    if (bid < 128) {
        float c = 0.0f;
        int idx = bid * 256 + threadIdx.x;
        if (idx < 26892) {
            int level, V, t;
            const float *pred, *bef; const int* lap;
            if (idx < 1284)      { level = 0; V = 642;   pred = p0; bef = b0p; lap = l0; t = idx; }
            else if (idx < 6408) { level = 1; V = 2562;  pred = p1; bef = b1p; lap = l1; t = idx - 1284; }
            else                 { level = 2; V = 10242; pred = p2; bef = b2p; lap = l2; t = idx - 6408; }
            int b = t / V;
            int v = t - b * V;
            const float* P  = pred + ((size_t)b * V + v) * 3;
            const float* Bf = bef  + ((size_t)b * V + v) * 3;
            float dx = Bf[0] - P[0], dy = Bf[1] - P[1], dz = Bf[2] - P[2];
            float sx = 0.f, sy = 0.f, sz = 0.f;
            const int* Lp = lap + v * 10;
            #pragma unroll
            for (int j = 0; j < 8; j++) {
                int n = Lp[j];
                if (n >= 0) {
                    const float* Pn = pred + ((size_t)b * V + n) * 3;
                    const float* Bn = bef  + ((size_t)b * V + n) * 3;
                    sx += Bn[0] - Pn[0]; sy += Bn[1] - Pn[1]; sz += Bn[2] - Pn[2];
                }
            }
            float invc = 1.0f / (float)Lp[9];
            float lx = dx - sx * invc, ly = dy - sy * invc, lz = dz - sz * invc;
            float sl = fmaf(lx, lx, fmaf(ly, ly, lz * lz));
            float sm = fmaf(dx, dx, fmaf(dy, dy, dz * dz));
            float lapc = (level == 0) ? 0.2f : 1.0f;
            float iBV = 1.0f / (2.0f * (float)V);
            c = sl * (0.5f * lapc * iBV) + ((level > 0) ? sm * (0.1f * lapc * iBV) : 0.0f);
        }
        c = blockReduceSum256(c);
        if (threadIdx.x == 0) ((float*)(ws + 8))[bid] = c;
        return;
    }
    int cid = bid - 128;
    int gtt = cid & 15;                // gt tile (512 pts)
    int t2 = cid >> 4;                 // 0..109
    int b = t2 >= 55 ? 1 : 0;
    int vt = t2 - 55 * b;
    int lvl, vtl, V, padOff, nt, tb;
    if (vt < 3)       { lvl = 0; vtl = vt;      V = 642;   padOff = 0;    nt = 3;  tb = 0; }
    else if (vt < 14) { lvl = 1; vtl = vt - 3;  V = 2562;  padOff = 768;  nt = 11; tb = 3; }
    else              { lvl = 2; vtl = vt - 14; V = 10242; padOff = 3584; nt = 41; tb = 14; }
    const float* predL = lvl == 0 ? p0 : (lvl == 1 ? p1 : p2);
    char* SA  = smem;            // 32 KB: 32 gt panels [panel][kgroup][row][16B]
    char* SB  = smem + 32768;    // 16 KB: 16 vert panels
    float* VML16 = (float*)smem; // loop-phase overlay: [256 vert][17] f32 (17,408 B)
    int tid = threadIdx.x;
    {   // stage 256 verts (wrap-duplicate tail; duplicates are min-safe)
        int v = vtl * 256 + tid;
        if (v >= V) v -= V;
        packVERT(predL + ((size_t)b * V + v) * 3, SB + (tid >> 4) * 1024 + (tid & 15) * 16);
    }
    #pragma unroll
    for (int k = 0; k < 2; k++) {    // stage 512 gts
        int j = tid + k * 256;
        packGT(gt + ((size_t)b * 8192 + gtt * 512 + j) * 3, SA + (j >> 4) * 1024 + (j & 15) * 16);
    }
    __syncthreads();
    float gmin[8][4];
    #pragma unroll
    for (int g = 0; g < 8; g++) {
        gmin[g][0] = 3.0e38f; gmin[g][1] = 3.0e38f; gmin[g][2] = 3.0e38f; gmin[g][3] = 3.0e38f;
    }
    int w = tid >> 6, L = tid & 63, lg = L >> 4;
    if (b == 0) {
        unsigned mask = STORE ? 0xFFFFFF80u : 0xFFFFF800u;  // 7-bit / 11-bit (+gtt) embed
        int eb = w * 32 + lg + (STORE ? 0 : (gtt << 7));
        mfmaLoop<true>(SA, SB, VML16, gmin, eb, mask);
    } else {
        mfmaLoop<false>(SA, SB, VML16, gmin, 0, 0u);
    }
    __syncthreads();                 // VML16 writes visible
    {   // vert partial: thread tid owns vert tid; reduce its 16 copies
        float pv = VML16[tid * 17];
        #pragma unroll
        for (int j = 1; j < 16; j++) pv = fminf(pv, VML16[tid * 17 + j]);
        int vs = b * 14080 + padOff + vtl * 256 + tid;
        if (STORE) {
            ((float*)(ws + PA_S))[(size_t)vs * 16 + gtt] = pv;
        } else {
            if (vtl * 256 + tid < V)
                atomicMin((unsigned*)(ws + PA_U) + vs, __float_as_uint(fmaxf(pv, 0.0f)));
        }
    }
    __syncthreads();                 // VML16 reads done -> reuse smem as GML
    float* GML = (float*)smem;       // [512 gt][stride 17] f32 = 34,816 B
    #pragma unroll
    for (int gg = 0; gg < 8; gg++) {
        #pragma unroll
        for (int r = 0; r < 4; r++)
            GML[(w * 128 + gg * 16 + lg * 4 + r) * 17 + (L & 15)] = gmin[gg][r];
    }
    __syncthreads();
    {   // gt partials: thread handles gts tid, tid+256; pB[(b,lvl)][m][tile]
        size_t pbBase = (size_t)b * 450560 + (lvl == 0 ? 0 : (lvl == 1 ? 24576 : 114688));
        #pragma unroll
        for (int k = 0; k < 2; k++) {
            int g = tid + k * 256;
            float q = 3.0e38f;
            #pragma unroll
            for (int cc = 0; cc < 16; cc++)
                q = fminf(q, GML[g * 17 + ((cc + tid) & 15)]);
            if (STORE) {
                ((float*)(ws + PB_S))[pbBase + (size_t)(gtt * 512 + g) * nt + vtl] = q;
            } else {
                atomicMin((unsigned*)(ws + PB_U) + (((b * 3 + lvl) << 13) + gtt * 512 + g),
                          __float_as_uint(fmaxf(q, 0.0f)));
            }
        }
    }
}

// combine: vert slots [0,28160) | gt slots [28160,77312) | lap-sum block 302
template<bool STORE>
__global__ __launch_bounds__(256) void kCombine2(
    const float* __restrict__ p0, const float* __restrict__ p1, const float* __restrict__ p2,
    const float* __restrict__ gt, char* ws)
{
    int bid = blockIdx.x, tid = threadIdx.x;
    float c = 0.0f;
    if (bid == 302) {
        if (tid < 128) c = ((float*)(ws + 8))[tid];
    } else {
        int idx = bid * 256 + tid;
        if (idx < 28160) {
            int b = idx >= 14080 ? 1 : 0;
            int q = idx - b * 14080;
            int lvl, V, lvlOff, padOff; const float* predL; float inv;
            if (q < 768)       { lvl=0; V=642;   padOff=0;    lvlOff=0;    predL=p0; inv=1.f/1284.f; }
            else if (q < 3584) { lvl=1; V=2562;  padOff=768;  lvlOff=642;  predL=p1; inv=1.f/5124.f; }
            else               { lvl=2; V=10242; padOff=3584; lvlOff=3204; predL=p2; inv=1.f/20484.f; }
            int v = q - padOff;
            if (v < V) {                               // skip wrap-duplicate slots
                float best; int bt = 0; unsigned bits;
                if (STORE) {
                    // contiguous 64B scan (4x float4)
                    const float4* P4 = (const float4*)((const float*)(ws + PA_S) + (size_t)idx * 16);
                    float4 a0 = P4[0], a1 = P4[1], a2 = P4[2], a3 = P4[3];
                    float vals[16] = {a0.x,a0.y,a0.z,a0.w, a1.x,a1.y,a1.z,a1.w,
                                      a2.x,a2.y,a2.z,a2.w, a3.x,a3.y,a3.z,a3.w};
                    best = vals[0];
                    #pragma unroll
                    for (int t = 1; t < 16; t++)
                        if (vals[t] < best) { best = vals[t]; bt = t; }
                    bits = __float_as_uint(best);
                } else {
                    bits = ((const unsigned*)(ws + PA_U))[idx];
                    best = __uint_as_float(bits);
                    bt = (bits >> 7) & 15;
                }
                float d;
                if (b == 0) {
                    // decode gt-group-of-4, recompute the 4 candidates exactly
                    int code = bits & 0x7F;
                    int m0 = bt * 512 + code * 4;
                    const float* pp = predL + (size_t)v * 3;
                    float px = pp[0], py = pp[1], pz = pp[2];
                    float bd = 3.0e38f; int bm = m0;
                    #pragma unroll
                    for (int u2 = 0; u2 < 4; u2++) {
                        const float* gp = gt + (size_t)(m0 + u2) * 3;
                        float dx = px - gp[0], dy = py - gp[1], dz = pz - gp[2];
                        float dd = fmaf(dx, dx, fmaf(dy, dy, dz * dz));
                        if (dd < bd) { bd = dd; bm = m0 + u2; }
                    }
                    ((int*)(ws + 1024))[lvlOff + v] = bm;
                    d = bd;
                } else {
                    d = best;                           // raw fp32, no embed for b=1
                }
                c = d * inv;
            }
        } else if (idx < 77312) {
            int r = idx - 28160;
            int b = r >= 24576 ? 1 : 0;
            int rem = r - b * 24576;
            int lvl = rem >> 13, m = rem & 8191;
            float d;
            if (STORE) {
                int nt = lvl == 0 ? 3 : (lvl == 1 ? 11 : 41);
                size_t pbBase = (size_t)b * 450560 + (lvl == 0 ? 0 : (lvl == 1 ? 24576 : 114688));
                const float* P = (const float*)(ws + PB_S) + pbBase + (size_t)m * nt;
                d = P[0];
                #pragma unroll 4
                for (int k2 = 1; k2 < nt; k2++) d = fminf(d, P[k2]);
            } else {
                d = __uint_as_float(((const unsigned*)(ws + PB_U))[((b * 3 + lvl) << 13) + m]);
            }
            c = d * (1.f / 16384.f);
        }
    }
    c = blockReduceSum256(c);
    if (tid == 0) atomicAdd((float*)ws, c);
}

// ---------- edge + normal + final output (ticket) ----------
__global__ __launch_bounds__(256) void kEdgeOut(
    const float* __restrict__ p0, const float* __restrict__ p1, const float* __restrict__ p2,
    const int* __restrict__ e0p, const int* __restrict__ e1p, const int* __restrict__ e2p,
    const float* __restrict__ gtn, char* ws, float* __restrict__ out)
{
    const int* knn = (const int*)(ws + 1024);
    int idx = blockIdx.x * 256 + threadIdx.x;
    float c = 0.0f;
    {
        int E, V, lvlOff, t;
        const float* pred; const int* edges;
        if (idx < 3840)       { E = 1920;  V = 642;   lvlOff = 0;    pred = p0; edges = e0p; t = idx; }
        else if (idx < 19200) { E = 7680;  V = 2562;  lvlOff = 642;  pred = p1; edges = e1p; t = idx - 3840; }
        else                  { E = 30720; V = 10242; lvlOff = 3204; pred = p2; edges = e2p; t = idx - 19200; }
        int b = t / E;
        int e = t % E;
        int a0 = edges[e * 2 + 0];
        int a1 = edges[e * 2 + 1];
        const float* P = pred + (size_t)b * V * 3;
        float dx = P[a0 * 3 + 0] - P[a1 * 3 + 0];
        float dy = P[a0 * 3 + 1] - P[a1 * 3 + 1];
        float dz = P[a0 * 3 + 2] - P[a1 * 3 + 2];
        float sq = fmaf(dx, dx, fmaf(dy, dy, dz * dz));
        float inv = 1.0f / fmaxf(sqrtf(sq), 1e-12f);
        int sel = knn[lvlOff + a0];                          // b=0 argmin
        const float* nr = gtn + ((size_t)b * 8192 + sel) * 3;
        float nx = nr[0], ny = nr[1], nz = nr[2];
        float invn = 1.0f / fmaxf(sqrtf(fmaf(nx, nx, fmaf(ny, ny, nz * nz))), 1e-12f);
        float dotv = fmaf(dx, nx, fmaf(dy, ny, dz * nz)) * inv * invn;
        float iBE = 1.0f / (2.0f * (float)E);
        c = sq * (0.1f * iBE) + fabsf(dotv) * (0.00016f * iBE);
    }
    c = blockReduceSum256(c);
    if (threadIdx.x == 0) {
        atomicAdd((float*)ws, c);
        __threadfence();
        unsigned t = atomicAdd((unsigned*)(ws + 4), 1u);
        if (t == 314u) out[0] = atomicAdd((float*)ws, 0.0f);
    }
}

extern "C" void kernel_launch(void* const* d_in, const int* in_sizes, int n_in,
                              void* d_out, int out_size, void* d_ws, size_t ws_size,
                              hipStream_t stream) {
    const float *gt, *gtn, *pred[3], *bef[3];
    const int *edg[3], *lapx[3];
    if (in_sizes[0] == 49152) {
        gt  = (const float*)d_in[0];
        gtn = (const float*)d_in[1];
        for (int i = 0; i < 3; i++) {
            pred[i] = (const float*)d_in[2 + 4 * i];
            bef[i]  = (const float*)d_in[3 + 4 * i];
            edg[i]  = (const int*)  d_in[4 + 4 * i];
            lapx[i] = (const int*)  d_in[5 + 4 * i];
        }
    } else {
        for (int i = 0; i < 3; i++) pred[i] = (const float*)d_in[i];
        for (int i = 0; i < 3; i++) bef[i]  = (const float*)d_in[3 + i];
        gt  = (const float*)d_in[6];
        gtn = (const float*)d_in[7];
        for (int i = 0; i < 3; i++) lapx[i] = (const int*)d_in[8 + i];
        for (int i = 0; i < 3; i++) edg[i]  = (const int*)d_in[11 + i];
    }

    char* ws = (char*)d_ws;
    bool store = ws_size >= (size_t)5462016;

    if (store) {
        kMega2<true><<<1888, 256, 49152, stream>>>(pred[0], pred[1], pred[2],
                                                   bef[0], bef[1], bef[2],
                                                   lapx[0], lapx[1], lapx[2], gt, ws);
        kCombine2<true><<<303, 256, 0, stream>>>(pred[0], pred[1], pred[2], gt, ws);
    } else {
        hipMemsetAsync(ws + PA_U, 0xFF, 364056 - PA_U, stream);   // mins = large
        kMega2<false><<<1888, 256, 49152, stream>>>(pred[0], pred[1], pred[2],
                                                    bef[0], bef[1], bef[2],
                                                    lapx[0], lapx[1], lapx[2], gt, ws);
        kCombine2<false><<<303, 256, 0, stream>>>(pred[0], pred[1], pred[2], gt, ws);
    }
    kEdgeOut<<<315, 256, 0, stream>>>(pred[0], pred[1], pred[2],
                                      edg[0], edg[1], edg[2], gtn, ws, (float*)d_out);
}